// Round 13
// baseline (6310.112 us; speedup 1.0000x reference)
//
#include <hip/hip_runtime.h>

typedef __bf16 bf16_t;
typedef __bf16 bf16x8 __attribute__((ext_vector_type(8)));
typedef float f32x4 __attribute__((ext_vector_type(4)));
typedef float f32x2 __attribute__((ext_vector_type(2)));
typedef unsigned u32x4 __attribute__((ext_vector_type(4)));

constexpr int kB = 64, kT = 256, kE = 128, kH = 1024, kV = 16384;
constexpr int kBT = kB * kT;

// ---- device-coherent (MALL-level) accesses: sc0 sc1 bypass L1+L2, pipelined.
__device__ __forceinline__ void ld16_sc(const void* p, u32x4& d) {
    asm volatile("global_load_dwordx4 %0, %1, off sc0 sc1" : "=v"(d) : "v"(p));
}
__device__ __forceinline__ void ld8_sc(const void* p, f32x2& d) {
    asm volatile("global_load_dwordx2 %0, %1, off sc0 sc1" : "=v"(d) : "v"(p));
}
__device__ __forceinline__ void ld8_c(const void* p, f32x2& d) {   // cached (read-only streams)
    asm volatile("global_load_dwordx2 %0, %1, off" : "=v"(d) : "v"(p));
}
__device__ __forceinline__ void st4_sc(void* p, unsigned v) {
    asm volatile("global_store_dword %0, %1, off sc0 sc1" :: "v"(p), "v"(v));
}
__device__ __forceinline__ void st8_sc(void* p, f32x2 v) {
    asm volatile("global_store_dwordx2 %0, %1, off sc0 sc1" :: "v"(p), "v"(v));
}
__device__ __forceinline__ unsigned ld_flag(const unsigned* p) {
    unsigned v;
    asm volatile("global_load_dword %0, %1, off sc0 sc1\n\ts_waitcnt vmcnt(0)"
                 : "=v"(v) : "v"(p) : "memory");
    return v;
}
#define WAITVM(n) asm volatile("s_waitcnt vmcnt(" #n ")" ::: "memory")

#define GL2LDS(gp, lp) __builtin_amdgcn_global_load_lds( \
    (const __attribute__((address_space(1))) void*)(gp), \
    (__attribute__((address_space(3))) void*)(lp), 16, 0, 0)

__device__ __forceinline__ unsigned pack_bf16(float a, float b) {
    union { unsigned u; __bf16 h[2]; } c;
    c.h[0] = (__bf16)a; c.h[1] = (__bf16)b;
    return c.u;
}
__device__ __forceinline__ f32x2 mk2(float a, float b) {
    f32x2 v; v[0] = a; v[1] = b; return v;
}

// ---------------- zero a byte range (multiple of 16) ----------------
__global__ void zero_bytes(char* p, size_t n) {
    size_t stride = (size_t)gridDim.x * blockDim.x * 16;
    for (size_t i = ((size_t)blockIdx.x * blockDim.x + threadIdx.x) * 16; i < n; i += stride) {
        uint4 z; z.x = z.y = z.z = z.w = 0;
        *reinterpret_cast<uint4*>(p + i) = z;
    }
}

// ---------------- transpose fp32 [R][C] -> bf16 [C][R] ----------------
__global__ void transpose_to_bf16(const float* __restrict__ src, bf16_t* __restrict__ dst,
                                  int R, int C) {
    __shared__ float tile[32][33];
    int c0 = blockIdx.x * 32, r0 = blockIdx.y * 32;
    for (int rr = threadIdx.y; rr < 32; rr += 8)
        tile[rr][threadIdx.x] = src[(size_t)(r0 + rr) * C + c0 + threadIdx.x];
    __syncthreads();
    for (int rr = threadIdx.y; rr < 32; rr += 8)
        dst[(size_t)(c0 + rr) * R + r0 + threadIdx.x] = (bf16_t)tile[threadIdx.x][rr];
}

// ---------------- embedding gather to bf16 [kBT][128] ----------------
__global__ __launch_bounds__(256) void embed_gather(const int* __restrict__ ids,
                                                    const float* __restrict__ emb,
                                                    bf16_t* __restrict__ XB) {
    int base = blockIdx.x * 16;
    for (int idx = threadIdx.x; idx < 16 * kE; idx += 256) {
        int r = idx >> 7, k = idx & 127;
        int row = base + r;
        XB[(size_t)row * kE + k] = (bf16_t)emb[(size_t)ids[row] * kE + k];
    }
}

// ---------------- x-precompute GEMM: C[M][N] = bias + XB[M][128] @ WT[N][128]^T ----
__global__ __launch_bounds__(256) void xpre_gemm(
    const bf16_t* __restrict__ XB, const bf16_t* __restrict__ WT,
    const float* __restrict__ bias, float* __restrict__ Cout, int N) {
    __shared__ __align__(16) char As[128 * 256];
    __shared__ __align__(16) char Bs[128 * 256];
    const int tid = threadIdx.x;
    const int w = tid >> 6, l = tid & 63, lr = l & 15, lk8 = (l >> 4) * 8;
    const int wr = w >> 1, wc = w & 1;
    const size_t row0 = (size_t)blockIdx.y * 128, col0 = (size_t)blockIdx.x * 128;
    for (int c = tid; c < 2048; c += 256) {
        int o = c * 16; int row = o >> 8; int kk = o & 255;
        int dst = (row << 8) + (kk ^ ((row & 7) << 4));
        *reinterpret_cast<bf16x8*>(As + dst) =
            *reinterpret_cast<const bf16x8*>(XB + (row0 + row) * kE + (kk >> 1));
        *reinterpret_cast<bf16x8*>(Bs + dst) =
            *reinterpret_cast<const bf16x8*>(WT + (col0 + row) * kE + (kk >> 1));
    }
    __syncthreads();
    f32x4 acc[4][4] = {};
    #pragma unroll
    for (int ks = 0; ks < 4; ++ks) {
        int kb = (ks * 32 + lk8) * 2;
        bf16x8 af[4], bfv[4];
        #pragma unroll
        for (int mf = 0; mf < 4; ++mf) {
            int r = wr * 64 + mf * 16 + lr;
            af[mf] = *reinterpret_cast<const bf16x8*>(As + (r << 8) + (kb ^ ((r & 7) << 4)));
        }
        #pragma unroll
        for (int nf = 0; nf < 4; ++nf) {
            int r = wc * 64 + nf * 16 + lr;
            bfv[nf] = *reinterpret_cast<const bf16x8*>(Bs + (r << 8) + (kb ^ ((r & 7) << 4)));
        }
        #pragma unroll
        for (int mf = 0; mf < 4; ++mf)
            #pragma unroll
            for (int nf = 0; nf < 4; ++nf)
                acc[mf][nf] = __builtin_amdgcn_mfma_f32_16x16x32_bf16(af[mf], bfv[nf], acc[mf][nf], 0, 0, 0);
    }
    #pragma unroll
    for (int mf = 0; mf < 4; ++mf) {
        size_t row = row0 + wr * 64 + mf * 16 + (l >> 4) * 4;
        #pragma unroll
        for (int nf = 0; nf < 4; ++nf) {
            size_t col = col0 + wc * 64 + nf * 16 + lr;
            float bvl = bias[col];
            #pragma unroll
            for (int i = 0; i < 4; ++i)
                Cout[(row + i) * (size_t)N + col] = acc[mf][nf][i] + bvl;
        }
    }
}

// ---------------- persistent RNN (exact round-6 structure, 4788 us) ----------------
struct PP {
    const bf16_t *WG1HT, *WC1HT, *WG2T, *WC2T;  // [N][K] bf16
    const float *XG1, *XC1;                     // [kB][kT][2048]/[1024] fp32
    const float *bg2, *bc2;
    float *H1F, *H2F, *U1, *U2;
    bf16_t *X2, *X2C0, *X2C1, *RH1, *YS;
    unsigned *flags;                            // 192 slots x 16 u32 (64B-padded)
};

// lanes [0,cnt) each poll ONE distinct 64B-padded flag (device-coherent load).
__device__ __forceinline__ void wait_flags(const unsigned* flags, int base, int cnt,
                                           unsigned tgt, int lane) {
    if ((unsigned)lane < (unsigned)cnt) {
        const unsigned* p = flags + (size_t)(base + lane) * 16;
        while (ld_flag(p) < tgt)
            __builtin_amdgcn_s_sleep(1);
    }
}

// Partial-K matmul: A[64][*] (pointer pre-offset) @ W_lds rows[n0..n0+32),
// cols [kbase,kbase+1024). Pipelined sc loads (depth-4, counted vmcnt).
template<int RBSH>
__device__ __forceinline__ void mm_part(const bf16_t* __restrict__ A, int astr,
                                        const char* __restrict__ wl, int kbase,
                                        int w, int lr, int lk, f32x4 (&acc)[4][2]) {
    const int kbeg = w * 256;                  // per-wave K chunk = 1024/4
    const bf16_t* base[4];
    #pragma unroll
    for (int mf = 0; mf < 4; ++mf)
        base[mf] = A + (size_t)(mf * 16 + lr) * astr + kbeg + lk;
    u32x4 buf[4][4];   // [depth][mf]
    #pragma unroll
    for (int pi = 0; pi < 4; ++pi)
        #pragma unroll
        for (int mf = 0; mf < 4; ++mf)
            ld16_sc(base[mf] + pi * 32, buf[pi][mf]);
    #pragma unroll
    for (int ki = 0; ki < 8; ++ki) {
        int rem = 7 - ki; if (rem > 3) rem = 3;    // folds to constant
        if (rem == 3)      WAITVM(12);
        else if (rem == 2) WAITVM(8);
        else if (rem == 1) WAITVM(4);
        else               WAITVM(0);
        __builtin_amdgcn_sched_barrier(0);
        #pragma unroll
        for (int nf = 0; nf < 2; ++nf) {
            int rr = nf * 16 + lr;
            int kb = (kbase + kbeg + ki * 32 + lk) * 2;
            bf16x8 wv = *reinterpret_cast<const bf16x8*>(wl + (rr << RBSH) + (kb ^ ((rr & 7) << 4)));
            #pragma unroll
            for (int mf = 0; mf < 4; ++mf)
                acc[mf][nf] = __builtin_amdgcn_mfma_f32_16x16x32_bf16(
                    __builtin_bit_cast(bf16x8, buf[ki & 3][mf]), wv, acc[mf][nf], 0, 0, 0);
        }
        if (ki + 4 < 8) {
            #pragma unroll
            for (int mf = 0; mf < 4; ++mf)
                ld16_sc(base[mf] + (ki + 4) * 32, buf[ki & 3][mf]);
        }
    }
}

// 192 blocks: [0,64)=gates1, [64,96)=cand1, [96,160)=gates2, [160,192)=cand2.
// Waits (r6-audited): P1(t): P2>=t | P2(t): P1>=t+1 (+deferred WAR P3>=t, P4>=t-1)
//   P3(t): early P4>=t; late P2>=t+1 | P4(t): early P2>=t+1; late P3>=t+1
__global__ __launch_bounds__(256, 1) void rnn_persistent(PP P) {
    __shared__ __align__(16) char wlds[131072];
    __shared__ float red[4][64][8];
    const int blk = blockIdx.x, tid = threadIdx.x;
    const int w = tid >> 6, l = tid & 63, lr = l & 15, lk = (l >> 4) * 8;
    int grp, idx;
    if (blk < 64)       { grp = 0; idx = blk; }
    else if (blk < 96)  { grp = 1; idx = blk - 64; }
    else if (blk < 160) { grp = 2; idx = blk - 96; }
    else                { grp = 3; idx = blk - 160; }
    const int n0 = idx * 32;
    const int K = (grp < 2) ? 1024 : 2048;
    const int rbsh = (grp < 2) ? 11 : 12;
    const bf16_t* Wsrc = (grp == 0) ? P.WG1HT : (grp == 1) ? P.WC1HT : (grp == 2) ? P.WG2T : P.WC2T;

    // stage weight slice rows [n0, n0+32) into LDS, XOR-swizzled within each row
    for (int c = tid; c < (32 * K * 2) / 16; c += 256) {
        int o = c * 16;
        int row = o >> rbsh;
        int kk = o & ((1 << rbsh) - 1);
        bf16x8 v = *reinterpret_cast<const bf16x8*>(Wsrc + (size_t)(n0 + row) * K + (kk >> 1));
        *reinterpret_cast<bf16x8*>(wlds + (row << rbsh) + (kk ^ ((row & 7) << 4))) = v;
    }
    __syncthreads();

    const unsigned* F = P.flags;
    const int r = tid >> 2, cb = (tid & 3) * 2;
    const bool lowhalf = (n0 < 1024);

    // biases preloaded (constant across t); own-h kept in registers for P2/P4
    f32x2 bx[4], hreg[4];
    #pragma unroll
    for (int p = 0; p < 4; ++p) {
        hreg[p] = mk2(0.f, 0.f);
        int j = n0 + p * 8 + cb;
        if (grp == 2)      bx[p] = *reinterpret_cast<const f32x2*>(P.bg2 + j);
        else if (grp == 3) bx[p] = *reinterpret_cast<const f32x2*>(P.bc2 + j);
    }

    for (int t = 0; t < kT; ++t) {
        unsigned ut = (unsigned)t;
        bf16_t* x2c = (t & 1) ? P.X2C1 : P.X2C0;
        f32x4 acc[4][2] = {};

        if (grp == 0) {
            if (t) wait_flags(F, 64, 32, ut, tid);
            __syncthreads();
            mm_part<11>(P.X2, 2048, wlds, 0, w, lr, lk, acc);
        } else if (grp == 1) {
            wait_flags(F, 0, 64, ut + 1, tid);
            __syncthreads();
            mm_part<11>(P.RH1, 1024, wlds, 0, w, lr, lk, acc);
            // deferred WAR (gates the stores below only)
            if (t) wait_flags(F, 96, 64, ut, tid);
            if (t >= 2) wait_flags(F, 160, 32, ut - 1, tid - 64);
            __syncthreads();
        } else if (grp == 2) {
            if (t) wait_flags(F, 160, 32, ut, tid);       // early: h2(t-1) from P4
            __syncthreads();
            mm_part<12>(P.X2 + 1024, 2048, wlds, 1024, w, lr, lk, acc);
            wait_flags(F, 64, 32, ut + 1, tid);           // late: h1(t) from P2
            __syncthreads();
            mm_part<12>(P.X2, 2048, wlds, 0, w, lr, lk, acc);
        } else {
            wait_flags(F, 64, 32, ut + 1, tid);           // early: h1(t) from P2
            __syncthreads();
            mm_part<12>(x2c, 2048, wlds, 0, w, lr, lk, acc);
            wait_flags(F, 96, 64, ut + 1, tid);           // late: r2h2(t) from P3
            __syncthreads();
            mm_part<12>(x2c + 1024, 2048, wlds, 1024, w, lr, lk, acc);
        }

        // ---- epilogue operand loads (pipelined, one drain) ----
        f32x2 pa[4], px[4];
        if (grp == 0) {
            #pragma unroll
            for (int p = 0; p < 4; ++p) {
                int j = n0 + p * 8 + cb;
                ld8_c(P.XG1 + ((size_t)r * kT + t) * 2048 + j, px[p]);
                if (lowhalf) ld8_sc(P.H1F + r * 1024 + j, pa[p]);
            }
        } else if (grp == 1) {
            #pragma unroll
            for (int p = 0; p < 4; ++p) {
                int j = n0 + p * 8 + cb;
                ld8_c(P.XC1 + ((size_t)r * kT + t) * 1024 + j, px[p]);
                ld8_sc(P.U1 + r * 1024 + j, pa[p]);
            }
        } else if (grp == 2) {
            #pragma unroll
            for (int p = 0; p < 4; ++p) {
                int j = n0 + p * 8 + cb;
                px[p] = bx[p];
                if (lowhalf) ld8_sc(P.H2F + r * 1024 + j, pa[p]);
            }
        } else {
            #pragma unroll
            for (int p = 0; p < 4; ++p) {
                int j = n0 + p * 8 + cb;
                px[p] = bx[p];
                ld8_sc(P.U2 + r * 1024 + j, pa[p]);
            }
        }
        asm volatile("s_waitcnt vmcnt(0)" ::: "memory");
        __builtin_amdgcn_sched_barrier(0);

        // cross-wave reduce + epilogue, 4 passes of 8 cols (red = 8 KB)
        #pragma unroll
        for (int p = 0; p < 4; ++p) {
            const int nf = p >> 1;
            if (((l >> 3) & 1) == (p & 1)) {
                #pragma unroll
                for (int mf = 0; mf < 4; ++mf)
                    #pragma unroll
                    for (int i = 0; i < 4; ++i)
                        red[w][mf * 16 + (l >> 4) * 4 + i][l & 7] = acc[mf][nf][i];
            }
            __syncthreads();
            {
                float v0 = red[0][r][cb] + red[1][r][cb] + red[2][r][cb] + red[3][r][cb];
                float v1 = red[0][r][cb + 1] + red[1][r][cb + 1] + red[2][r][cb + 1] + red[3][r][cb + 1];
                int j = n0 + p * 8 + cb;
                v0 += px[p][0]; v1 += px[p][1];
                if (grp == 0) {
                    float g0 = 1.f / (1.f + __expf(-v0));
                    float g1 = 1.f / (1.f + __expf(-v1));
                    if (lowhalf) {
                        st4_sc(P.RH1 + r * 1024 + j, pack_bf16(g0 * pa[p][0], g1 * pa[p][1]));
                    } else {
                        st8_sc(P.U1 + r * 1024 + j - 1024, mk2(g0, g1));
                    }
                } else if (grp == 1) {
                    float cc0 = tanhf(v0), cc1 = tanhf(v1);
                    float hn0 = pa[p][0] * hreg[p][0] + (1.f - pa[p][0]) * cc0;
                    float hn1 = pa[p][1] * hreg[p][1] + (1.f - pa[p][1]) * cc1;
                    hreg[p] = mk2(hn0, hn1);
                    st8_sc(P.H1F + r * 1024 + j, hreg[p]);
                    unsigned pk = pack_bf16(hn0, hn1);
                    st4_sc(P.X2 + r * 2048 + j, pk);
                    st4_sc(x2c + r * 2048 + j, pk);
                } else if (grp == 2) {
                    float g0 = 1.f / (1.f + __expf(-v0));
                    float g1 = 1.f / (1.f + __expf(-v1));
                    if (lowhalf) {
                        st4_sc(x2c + r * 2048 + 1024 + j, pack_bf16(g0 * pa[p][0], g1 * pa[p][1]));
                    } else {
                        st8_sc(P.U2 + r * 1024 + j - 1024, mk2(g0, g1));
                    }
                } else {
                    float cc0 = tanhf(v0), cc1 = tanhf(v1);
                    float hn0 = pa[p][0] * hreg[p][0] + (1.f - pa[p][0]) * cc0;
                    float hn1 = pa[p][1] * hreg[p][1] + (1.f - pa[p][1]) * cc1;
                    hreg[p] = mk2(hn0, hn1);
                    st8_sc(P.H2F + r * 1024 + j, hreg[p]);
                    unsigned pk = pack_bf16(hn0, hn1);
                    st4_sc(P.X2 + r * 2048 + 1024 + j, pk);
                    *reinterpret_cast<unsigned*>(P.YS + ((size_t)r * kT + t) * 1024 + j) = pk;
                }
            }
            __syncthreads();
        }

        // release: drain all stores, barrier, publish flag.
        asm volatile("s_waitcnt vmcnt(0)" ::: "memory");
        __syncthreads();
        if (tid == 0)
            st4_sc((void*)&F[(size_t)blk * 16], ut + 1);
    }
}

// ---------------- logits GEMM (2-phase gl2lds pipeline + XCD swizzle + fused NLL) ----
// T3-min recipe: issue next tile's stage BEFORE computing current; one
// vmcnt(0)+barrier per K-tile (stage latency hidden under 32 MFMAs).
// PM[c][row] (f32x2): per-row (max, sumexp) over 64-col chunk c (c in [0,256)).
__global__ __launch_bounds__(256) void logits_gemm(
    const bf16_t* __restrict__ Amat,   // [kBT][kH]
    const bf16_t* __restrict__ Bt,     // [kV][kH]
    const float* __restrict__ bias,    // [kV]
    float* __restrict__ out,           // [kBT][kV]
    float* __restrict__ PM) {          // [256][kBT][2]
    __shared__ __align__(16) bf16_t As[2][128 * 64];
    __shared__ __align__(16) bf16_t Bs[2][128 * 64];
    const int tid = threadIdx.x;
    const int w = tid >> 6, l = tid & 63;
    const int wr = w >> 1, wc = w & 1;
    const int lr = l & 15, lk8 = (l >> 4) * 8;
    // bijective XCD swizzle (16384 blocks, 16384 % 8 == 0)
    int lin = blockIdx.y * gridDim.x + blockIdx.x;
    int s = (lin & 7) * 2048 + (lin >> 3);
    const int row0 = (s >> 7) * 128, col0 = (s & 127) * 128;

    int srow[4], scol[4];
    #pragma unroll
    for (int v = 0; v < 4; ++v) {
        int idx = v * 256 + tid;
        srow[v] = idx >> 3;
        scol[v] = (idx & 7) * 8;
    }

    f32x4 acc[4][4] = {};
    // prologue: stage kt=0 into buffer 0, drain, barrier
    #pragma unroll
    for (int v = 0; v < 4; ++v) {
        GL2LDS(Amat + (size_t)(row0 + srow[v]) * kH + scol[v], As[0] + srow[v] * 64 + scol[v]);
        GL2LDS(Bt + (size_t)(col0 + srow[v]) * kH + scol[v], Bs[0] + srow[v] * 64 + scol[v]);
    }
    WAITVM(0);
    __syncthreads();
    int cur = 0;
    for (int kt = 0; kt < 16; ++kt) {
        if (kt < 15) {
            int ko = (kt + 1) * 64;           // stage NEXT tile into buf[cur^1]
            #pragma unroll
            for (int v = 0; v < 4; ++v) {
                GL2LDS(Amat + (size_t)(row0 + srow[v]) * kH + ko + scol[v], As[cur ^ 1] + srow[v] * 64 + scol[v]);
                GL2LDS(Bt + (size_t)(col0 + srow[v]) * kH + ko + scol[v], Bs[cur ^ 1] + srow[v] * 64 + scol[v]);
            }
        }
        #pragma unroll
        for (int ks = 0; ks < 2; ++ks) {       // compute CURRENT tile
            bf16x8 af[4], bfv[4];
            #pragma unroll
            for (int mf = 0; mf < 4; ++mf)
                af[mf] = *reinterpret_cast<const bf16x8*>(As[cur] + (wr * 64 + mf * 16 + lr) * 64 + ks * 32 + lk8);
            #pragma unroll
            for (int nf = 0; nf < 4; ++nf)
                bfv[nf] = *reinterpret_cast<const bf16x8*>(Bs[cur] + (wc * 64 + nf * 16 + lr) * 64 + ks * 32 + lk8);
            #pragma unroll
            for (int mf = 0; mf < 4; ++mf)
                #pragma unroll
                for (int nf = 0; nf < 4; ++nf)
                    acc[mf][nf] = __builtin_amdgcn_mfma_f32_16x16x32_bf16(af[mf], bfv[nf], acc[mf][nf], 0, 0, 0);
        }
        if (kt < 15) {
            WAITVM(0);                         // next tile's 8 loads landed
            __syncthreads();                   // all waves done reading buf[cur]
            cur ^= 1;
        }
    }
    // epilogue: bias add + store + per-row (max,sumexp) partial over this wave's 64 cols
    const int chunk = (col0 >> 6) + wc;        // [0,256)
    #pragma unroll
    for (int mf = 0; mf < 4; ++mf) {
        #pragma unroll
        for (int i = 0; i < 4; ++i) {
            int row = row0 + wr * 64 + mf * 16 + (l >> 4) * 4 + i;
            float vals[4];
            #pragma unroll
            for (int nf = 0; nf < 4; ++nf) {
                int col = col0 + wc * 64 + nf * 16 + lr;
                vals[nf] = acc[mf][nf][i] + bias[col];
                out[(size_t)row * kV + col] = vals[nf];
            }
            float m = fmaxf(fmaxf(vals[0], vals[1]), fmaxf(vals[2], vals[3]));
            float sm = __expf(vals[0] - m) + __expf(vals[1] - m)
                     + __expf(vals[2] - m) + __expf(vals[3] - m);
            #pragma unroll
            for (int d = 1; d < 16; d <<= 1) {
                float m2 = __shfl_xor(m, d);
                float s2 = __shfl_xor(sm, d);
                float M = fmaxf(m, m2);
                sm = sm * __expf(m - M) + s2 * __expf(m2 - M);
                m = M;
            }
            if (lr == 0)
                *reinterpret_cast<f32x2*>(PM + ((size_t)chunk * kBT + row) * 2) = mk2(m, sm);
        }
    }
}

// ---------------- NLL finalize: combine 256 chunk-partials per row ----------------
__global__ __launch_bounds__(256) void nll_finalize(const float* __restrict__ PM,
                                                    const float* __restrict__ logits,
                                                    const int* __restrict__ targets,
                                                    float* __restrict__ nll) {
    int row = blockIdx.x * 256 + threadIdx.x;
    float m = -1e30f, s = 0.f;
    #pragma unroll 4
    for (int c = 0; c < 256; ++c) {
        f32x2 p = *reinterpret_cast<const f32x2*>(PM + ((size_t)c * kBT + row) * 2);
        float M = fmaxf(m, p[0]);
        s = s * __expf(m - M) + p[1] * __expf(p[0] - M);
        m = M;
    }
    float tl = logits[(size_t)row * kV + targets[row]];
    nll[row] = m + __logf(s) - tl;
}

__global__ __launch_bounds__(256) void loss_reduce(const float* __restrict__ nll,
                                                   float* __restrict__ out) {
    __shared__ float sm[256];
    int tid = threadIdx.x;
    float s = 0.f;
    for (int i = tid; i < kBT; i += 256) s += nll[i];
    sm[tid] = s;
    __syncthreads();
    for (int off = 128; off; off >>= 1) {
        if (tid < off) sm[tid] += sm[tid + off];
        __syncthreads();
    }
    if (tid == 0) out[0] = sm[0] / (float)kBT;
}

// ---------------- host ----------------
extern "C" void kernel_launch(void* const* d_in, const int* in_sizes, int n_in,
                              void* d_out, int out_size, void* d_ws, size_t ws_size,
                              hipStream_t stream) {
    const int*   ids = (const int*)d_in[0];
    const int*   tgt = (const int*)d_in[1];
    const float* emb = (const float*)d_in[2];
    const float* Wg1 = (const float*)d_in[3];
    const float* bg1 = (const float*)d_in[4];
    const float* Wc1 = (const float*)d_in[5];
    const float* bc1 = (const float*)d_in[6];
    const float* Wg2 = (const float*)d_in[7];
    const float* bg2 = (const float*)d_in[8];
    const float* Wc2 = (const float*)d_in[9];
    const float* bc2 = (const float*)d_in[10];
    const float* sw  = (const float*)d_in[11];
    const float* sb  = (const float*)d_in[12];
    float* out = (float*)d_out;

    char* ws = (char*)d_ws;
    size_t off = 0;
    auto alloc = [&](size_t bytes) -> void* {
        void* p = ws + off;
        off += (bytes + 255) & ~(size_t)255;
        return p;
    };
    bf16_t* WG1HT = (bf16_t*)alloc((size_t)2048 * 1024 * 2);
    bf16_t* WC1HT = (bf16_t*)alloc((size_t)1024 * 1024 * 2);
    bf16_t* WG2T  = (bf16_t*)alloc((size_t)2048 * 2048 * 2);
    bf16_t* WC2T  = (bf16_t*)alloc((size_t)1024 * 2048 * 2);
    bf16_t* SWT   = (bf16_t*)alloc((size_t)kV * kH * 2);
    bf16_t* WG1XT = (bf16_t*)alloc((size_t)2048 * kE * 2);
    bf16_t* WC1XT = (bf16_t*)alloc((size_t)1024 * kE * 2);
    bf16_t* XB    = (bf16_t*)alloc((size_t)kBT * kE * 2);
    float*  XG1   = (float*)alloc((size_t)kBT * 2048 * 4);
    float*  XC1   = (float*)alloc((size_t)kBT * 1024 * 4);
    bf16_t* YS    = (bf16_t*)alloc((size_t)kBT * kH * 2);
    float*  NLL   = (float*)alloc((size_t)kBT * 4);
    float*  PM    = (float*)alloc((size_t)256 * kBT * 2 * 4);
    // ---- contiguous zero region start ----
    char*   zbase = ws + off;
    float*  H1F   = (float*)alloc((size_t)kB * kH * 4);
    float*  H2F   = (float*)alloc((size_t)kB * kH * 4);
    float*  U1    = (float*)alloc((size_t)kB * kH * 4);
    float*  U2    = (float*)alloc((size_t)kB * kH * 4);
    bf16_t* X2    = (bf16_t*)alloc((size_t)kB * 2048 * 2);
    bf16_t* X2C0  = (bf16_t*)alloc((size_t)kB * 2048 * 2);
    bf16_t* X2C1  = (bf16_t*)alloc((size_t)kB * 2048 * 2);
    bf16_t* RH1   = (bf16_t*)alloc((size_t)kB * kH * 2);
    unsigned* FLAGS = (unsigned*)alloc(192 * 16 * 4);
    size_t zlen = (ws + off) - zbase;
    // ---- contiguous zero region end ----

    // weight conversions (bf16, [N][K] layout)
    transpose_to_bf16<<<dim3(64, 32), dim3(32, 8), 0, stream>>>(Wg1 + (size_t)kE * 2048, WG1HT, 1024, 2048);
    transpose_to_bf16<<<dim3(32, 32), dim3(32, 8), 0, stream>>>(Wc1 + (size_t)kE * 1024, WC1HT, 1024, 1024);
    transpose_to_bf16<<<dim3(64, 64), dim3(32, 8), 0, stream>>>(Wg2, WG2T, 2048, 2048);
    transpose_to_bf16<<<dim3(32, 64), dim3(32, 8), 0, stream>>>(Wc2, WC2T, 2048, 1024);
    transpose_to_bf16<<<dim3(512, 32), dim3(32, 8), 0, stream>>>(sw, SWT, 1024, 16384);
    transpose_to_bf16<<<dim3(64, 4), dim3(32, 8), 0, stream>>>(Wg1, WG1XT, 128, 2048);
    transpose_to_bf16<<<dim3(32, 4), dim3(32, 8), 0, stream>>>(Wc1, WC1XT, 128, 1024);

    embed_gather<<<kBT / 16, 256, 0, stream>>>(ids, emb, XB);
    xpre_gemm<<<dim3(16, kBT / 128), 256, 0, stream>>>(XB, WG1XT, bg1, XG1, 2048);
    xpre_gemm<<<dim3(8, kBT / 128), 256, 0, stream>>>(XB, WC1XT, bc1, XC1, 1024);
    zero_bytes<<<256, 256, 0, stream>>>(zbase, zlen);

    PP prm;
    prm.WG1HT = WG1HT; prm.WC1HT = WC1HT; prm.WG2T = WG2T; prm.WC2T = WC2T;
    prm.XG1 = XG1; prm.XC1 = XC1; prm.bg2 = bg2; prm.bc2 = bc2;
    prm.H1F = H1F; prm.H2F = H2F; prm.U1 = U1; prm.U2 = U2;
    prm.X2 = X2; prm.X2C0 = X2C0; prm.X2C1 = X2C1; prm.RH1 = RH1; prm.YS = YS;
    prm.flags = FLAGS;
    void* args[] = { &prm };
    hipLaunchCooperativeKernel((const void*)rnn_persistent, dim3(192), dim3(256), args, 0, stream);

    logits_gemm<<<dim3(kV / 128, kBT / 128), 256, 0, stream>>>(YS, SWT, sb, out, PM);
    nll_finalize<<<kBT / 256, 256, 0, stream>>>(PM, out, tgt, NLL);
    loss_reduce<<<1, 256, 0, stream>>>(NLL, out + (size_t)kBT * kV);
}

// Round 14
// 6079.602 us; speedup vs baseline: 1.0379x; 1.0379x over previous
//
#include <hip/hip_runtime.h>

typedef __bf16 bf16_t;
typedef __bf16 bf16x8 __attribute__((ext_vector_type(8)));
typedef float f32x4 __attribute__((ext_vector_type(4)));
typedef float f32x2 __attribute__((ext_vector_type(2)));
typedef unsigned u32x4 __attribute__((ext_vector_type(4)));

constexpr int kB = 64, kT = 256, kE = 128, kH = 1024, kV = 16384;
constexpr int kBT = kB * kT;

// ---- device-coherent (MALL-level) accesses: sc0 sc1 bypass L1+L2, pipelined.
__device__ __forceinline__ void ld16_sc(const void* p, u32x4& d) {
    asm volatile("global_load_dwordx4 %0, %1, off sc0 sc1" : "=v"(d) : "v"(p));
}
__device__ __forceinline__ void ld8_sc(const void* p, f32x2& d) {
    asm volatile("global_load_dwordx2 %0, %1, off sc0 sc1" : "=v"(d) : "v"(p));
}
__device__ __forceinline__ void ld8_c(const void* p, f32x2& d) {   // cached (read-only streams)
    asm volatile("global_load_dwordx2 %0, %1, off" : "=v"(d) : "v"(p));
}
__device__ __forceinline__ void st4_sc(void* p, unsigned v) {
    asm volatile("global_store_dword %0, %1, off sc0 sc1" :: "v"(p), "v"(v));
}
__device__ __forceinline__ void st8_sc(void* p, f32x2 v) {
    asm volatile("global_store_dwordx2 %0, %1, off sc0 sc1" :: "v"(p), "v"(v));
}
__device__ __forceinline__ unsigned ld_flag(const unsigned* p) {
    unsigned v;
    asm volatile("global_load_dword %0, %1, off sc0 sc1\n\ts_waitcnt vmcnt(0)"
                 : "=v"(v) : "v"(p) : "memory");
    return v;
}
#define WAITVM(n) asm volatile("s_waitcnt vmcnt(" #n ")" ::: "memory")

#define GL2LDS(gp, lp) __builtin_amdgcn_global_load_lds( \
    (const __attribute__((address_space(1))) void*)(gp), \
    (__attribute__((address_space(3))) void*)(lp), 16, 0, 0)

__device__ __forceinline__ unsigned pack_bf16(float a, float b) {
    union { unsigned u; __bf16 h[2]; } c;
    c.h[0] = (__bf16)a; c.h[1] = (__bf16)b;
    return c.u;
}
__device__ __forceinline__ f32x2 mk2(float a, float b) {
    f32x2 v; v[0] = a; v[1] = b; return v;
}

// ---------------- zero a byte range (multiple of 16) ----------------
__global__ void zero_bytes(char* p, size_t n) {
    size_t stride = (size_t)gridDim.x * blockDim.x * 16;
    for (size_t i = ((size_t)blockIdx.x * blockDim.x + threadIdx.x) * 16; i < n; i += stride) {
        uint4 z; z.x = z.y = z.z = z.w = 0;
        *reinterpret_cast<uint4*>(p + i) = z;
    }
}

// ---------------- transpose fp32 [R][C] -> bf16 [C][R] ----------------
__global__ void transpose_to_bf16(const float* __restrict__ src, bf16_t* __restrict__ dst,
                                  int R, int C) {
    __shared__ float tile[32][33];
    int c0 = blockIdx.x * 32, r0 = blockIdx.y * 32;
    for (int rr = threadIdx.y; rr < 32; rr += 8)
        tile[rr][threadIdx.x] = src[(size_t)(r0 + rr) * C + c0 + threadIdx.x];
    __syncthreads();
    for (int rr = threadIdx.y; rr < 32; rr += 8)
        dst[(size_t)(c0 + rr) * R + r0 + threadIdx.x] = (bf16_t)tile[threadIdx.x][rr];
}

// ---------------- embedding gather to bf16 [kBT][128] ----------------
__global__ __launch_bounds__(256) void embed_gather(const int* __restrict__ ids,
                                                    const float* __restrict__ emb,
                                                    bf16_t* __restrict__ XB) {
    int base = blockIdx.x * 16;
    for (int idx = threadIdx.x; idx < 16 * kE; idx += 256) {
        int r = idx >> 7, k = idx & 127;
        int row = base + r;
        XB[(size_t)row * kE + k] = (bf16_t)emb[(size_t)ids[row] * kE + k];
    }
}

// ---------------- x-precompute GEMM: C[M][N] = bias + XB[M][128] @ WT[N][128]^T ----
__global__ __launch_bounds__(256) void xpre_gemm(
    const bf16_t* __restrict__ XB, const bf16_t* __restrict__ WT,
    const float* __restrict__ bias, float* __restrict__ Cout, int N) {
    __shared__ __align__(16) char As[128 * 256];
    __shared__ __align__(16) char Bs[128 * 256];
    const int tid = threadIdx.x;
    const int w = tid >> 6, l = tid & 63, lr = l & 15, lk8 = (l >> 4) * 8;
    const int wr = w >> 1, wc = w & 1;
    const size_t row0 = (size_t)blockIdx.y * 128, col0 = (size_t)blockIdx.x * 128;
    for (int c = tid; c < 2048; c += 256) {
        int o = c * 16; int row = o >> 8; int kk = o & 255;
        int dst = (row << 8) + (kk ^ ((row & 7) << 4));
        *reinterpret_cast<bf16x8*>(As + dst) =
            *reinterpret_cast<const bf16x8*>(XB + (row0 + row) * kE + (kk >> 1));
        *reinterpret_cast<bf16x8*>(Bs + dst) =
            *reinterpret_cast<const bf16x8*>(WT + (col0 + row) * kE + (kk >> 1));
    }
    __syncthreads();
    f32x4 acc[4][4] = {};
    #pragma unroll
    for (int ks = 0; ks < 4; ++ks) {
        int kb = (ks * 32 + lk8) * 2;
        bf16x8 af[4], bfv[4];
        #pragma unroll
        for (int mf = 0; mf < 4; ++mf) {
            int r = wr * 64 + mf * 16 + lr;
            af[mf] = *reinterpret_cast<const bf16x8*>(As + (r << 8) + (kb ^ ((r & 7) << 4)));
        }
        #pragma unroll
        for (int nf = 0; nf < 4; ++nf) {
            int r = wc * 64 + nf * 16 + lr;
            bfv[nf] = *reinterpret_cast<const bf16x8*>(Bs + (r << 8) + (kb ^ ((r & 7) << 4)));
        }
        #pragma unroll
        for (int mf = 0; mf < 4; ++mf)
            #pragma unroll
            for (int nf = 0; nf < 4; ++nf)
                acc[mf][nf] = __builtin_amdgcn_mfma_f32_16x16x32_bf16(af[mf], bfv[nf], acc[mf][nf], 0, 0, 0);
    }
    #pragma unroll
    for (int mf = 0; mf < 4; ++mf) {
        size_t row = row0 + wr * 64 + mf * 16 + (l >> 4) * 4;
        #pragma unroll
        for (int nf = 0; nf < 4; ++nf) {
            size_t col = col0 + wc * 64 + nf * 16 + lr;
            float bvl = bias[col];
            #pragma unroll
            for (int i = 0; i < 4; ++i)
                Cout[(row + i) * (size_t)N + col] = acc[mf][nf][i] + bvl;
        }
    }
}

// ---------------- persistent RNN (exact round-6 structure, 4788 us) ----------------
struct PP {
    const bf16_t *WG1HT, *WC1HT, *WG2T, *WC2T;  // [N][K] bf16
    const float *XG1, *XC1;                     // [kB][kT][2048]/[1024] fp32
    const float *bg2, *bc2;
    float *H1F, *H2F, *U1, *U2;
    bf16_t *X2, *X2C0, *X2C1, *RH1, *YS;
    unsigned *flags;                            // 192 slots x 16 u32 (64B-padded)
};

// lanes [0,cnt) each poll ONE distinct 64B-padded flag (device-coherent load).
__device__ __forceinline__ void wait_flags(const unsigned* flags, int base, int cnt,
                                           unsigned tgt, int lane) {
    if ((unsigned)lane < (unsigned)cnt) {
        const unsigned* p = flags + (size_t)(base + lane) * 16;
        while (ld_flag(p) < tgt)
            __builtin_amdgcn_s_sleep(1);
    }
}

// Partial-K matmul: A[64][*] (pointer pre-offset) @ W_lds rows[n0..n0+32),
// cols [kbase,kbase+1024). Pipelined sc loads (depth-4, counted vmcnt).
template<int RBSH>
__device__ __forceinline__ void mm_part(const bf16_t* __restrict__ A, int astr,
                                        const char* __restrict__ wl, int kbase,
                                        int w, int lr, int lk, f32x4 (&acc)[4][2]) {
    const int kbeg = w * 256;                  // per-wave K chunk = 1024/4
    const bf16_t* base[4];
    #pragma unroll
    for (int mf = 0; mf < 4; ++mf)
        base[mf] = A + (size_t)(mf * 16 + lr) * astr + kbeg + lk;
    u32x4 buf[4][4];   // [depth][mf]
    #pragma unroll
    for (int pi = 0; pi < 4; ++pi)
        #pragma unroll
        for (int mf = 0; mf < 4; ++mf)
            ld16_sc(base[mf] + pi * 32, buf[pi][mf]);
    #pragma unroll
    for (int ki = 0; ki < 8; ++ki) {
        int rem = 7 - ki; if (rem > 3) rem = 3;    // folds to constant
        if (rem == 3)      WAITVM(12);
        else if (rem == 2) WAITVM(8);
        else if (rem == 1) WAITVM(4);
        else               WAITVM(0);
        __builtin_amdgcn_sched_barrier(0);
        #pragma unroll
        for (int nf = 0; nf < 2; ++nf) {
            int rr = nf * 16 + lr;
            int kb = (kbase + kbeg + ki * 32 + lk) * 2;
            bf16x8 wv = *reinterpret_cast<const bf16x8*>(wl + (rr << RBSH) + (kb ^ ((rr & 7) << 4)));
            #pragma unroll
            for (int mf = 0; mf < 4; ++mf)
                acc[mf][nf] = __builtin_amdgcn_mfma_f32_16x16x32_bf16(
                    __builtin_bit_cast(bf16x8, buf[ki & 3][mf]), wv, acc[mf][nf], 0, 0, 0);
        }
        if (ki + 4 < 8) {
            #pragma unroll
            for (int mf = 0; mf < 4; ++mf)
                ld16_sc(base[mf] + (ki + 4) * 32, buf[ki & 3][mf]);
        }
    }
}

// 192 blocks: [0,64)=gates1, [64,96)=cand1, [96,160)=gates2, [160,192)=cand2.
// Waits (r6-audited): P1(t): P2>=t | P2(t): P1>=t+1 (+deferred WAR P3>=t, P4>=t-1)
//   P3(t): early P4>=t; late P2>=t+1 | P4(t): early P2>=t+1; late P3>=t+1
__global__ __launch_bounds__(256, 1) void rnn_persistent(PP P) {
    __shared__ __align__(16) char wlds[131072];
    __shared__ float red[4][64][8];
    const int blk = blockIdx.x, tid = threadIdx.x;
    const int w = tid >> 6, l = tid & 63, lr = l & 15, lk = (l >> 4) * 8;
    int grp, idx;
    if (blk < 64)       { grp = 0; idx = blk; }
    else if (blk < 96)  { grp = 1; idx = blk - 64; }
    else if (blk < 160) { grp = 2; idx = blk - 96; }
    else                { grp = 3; idx = blk - 160; }
    const int n0 = idx * 32;
    const int K = (grp < 2) ? 1024 : 2048;
    const int rbsh = (grp < 2) ? 11 : 12;
    const bf16_t* Wsrc = (grp == 0) ? P.WG1HT : (grp == 1) ? P.WC1HT : (grp == 2) ? P.WG2T : P.WC2T;

    // stage weight slice rows [n0, n0+32) into LDS, XOR-swizzled within each row
    for (int c = tid; c < (32 * K * 2) / 16; c += 256) {
        int o = c * 16;
        int row = o >> rbsh;
        int kk = o & ((1 << rbsh) - 1);
        bf16x8 v = *reinterpret_cast<const bf16x8*>(Wsrc + (size_t)(n0 + row) * K + (kk >> 1));
        *reinterpret_cast<bf16x8*>(wlds + (row << rbsh) + (kk ^ ((row & 7) << 4))) = v;
    }
    __syncthreads();

    const unsigned* F = P.flags;
    const int r = tid >> 2, cb = (tid & 3) * 2;
    const bool lowhalf = (n0 < 1024);

    // biases preloaded (constant across t); own-h kept in registers for P2/P4
    f32x2 bx[4], hreg[4];
    #pragma unroll
    for (int p = 0; p < 4; ++p) {
        hreg[p] = mk2(0.f, 0.f);
        int j = n0 + p * 8 + cb;
        if (grp == 2)      bx[p] = *reinterpret_cast<const f32x2*>(P.bg2 + j);
        else if (grp == 3) bx[p] = *reinterpret_cast<const f32x2*>(P.bc2 + j);
    }

    for (int t = 0; t < kT; ++t) {
        unsigned ut = (unsigned)t;
        bf16_t* x2c = (t & 1) ? P.X2C1 : P.X2C0;
        f32x4 acc[4][2] = {};

        if (grp == 0) {
            if (t) wait_flags(F, 64, 32, ut, tid);
            __syncthreads();
            mm_part<11>(P.X2, 2048, wlds, 0, w, lr, lk, acc);
        } else if (grp == 1) {
            wait_flags(F, 0, 64, ut + 1, tid);
            __syncthreads();
            mm_part<11>(P.RH1, 1024, wlds, 0, w, lr, lk, acc);
            // deferred WAR (gates the stores below only)
            if (t) wait_flags(F, 96, 64, ut, tid);
            if (t >= 2) wait_flags(F, 160, 32, ut - 1, tid - 64);
            __syncthreads();
        } else if (grp == 2) {
            if (t) wait_flags(F, 160, 32, ut, tid);       // early: h2(t-1) from P4
            __syncthreads();
            mm_part<12>(P.X2 + 1024, 2048, wlds, 1024, w, lr, lk, acc);
            wait_flags(F, 64, 32, ut + 1, tid);           // late: h1(t) from P2
            __syncthreads();
            mm_part<12>(P.X2, 2048, wlds, 0, w, lr, lk, acc);
        } else {
            wait_flags(F, 64, 32, ut + 1, tid);           // early: h1(t) from P2
            __syncthreads();
            mm_part<12>(x2c, 2048, wlds, 0, w, lr, lk, acc);
            wait_flags(F, 96, 64, ut + 1, tid);           // late: r2h2(t) from P3
            __syncthreads();
            mm_part<12>(x2c + 1024, 2048, wlds, 1024, w, lr, lk, acc);
        }

        // ---- epilogue operand loads (pipelined, one drain) ----
        f32x2 pa[4], px[4];
        if (grp == 0) {
            #pragma unroll
            for (int p = 0; p < 4; ++p) {
                int j = n0 + p * 8 + cb;
                ld8_c(P.XG1 + ((size_t)r * kT + t) * 2048 + j, px[p]);
                if (lowhalf) ld8_sc(P.H1F + r * 1024 + j, pa[p]);
            }
        } else if (grp == 1) {
            #pragma unroll
            for (int p = 0; p < 4; ++p) {
                int j = n0 + p * 8 + cb;
                ld8_c(P.XC1 + ((size_t)r * kT + t) * 1024 + j, px[p]);
                ld8_sc(P.U1 + r * 1024 + j, pa[p]);
            }
        } else if (grp == 2) {
            #pragma unroll
            for (int p = 0; p < 4; ++p) {
                int j = n0 + p * 8 + cb;
                px[p] = bx[p];
                if (lowhalf) ld8_sc(P.H2F + r * 1024 + j, pa[p]);
            }
        } else {
            #pragma unroll
            for (int p = 0; p < 4; ++p) {
                int j = n0 + p * 8 + cb;
                px[p] = bx[p];
                ld8_sc(P.U2 + r * 1024 + j, pa[p]);
            }
        }
        asm volatile("s_waitcnt vmcnt(0)" ::: "memory");
        __builtin_amdgcn_sched_barrier(0);

        // cross-wave reduce + epilogue, 4 passes of 8 cols (red = 8 KB)
        #pragma unroll
        for (int p = 0; p < 4; ++p) {
            const int nf = p >> 1;
            if (((l >> 3) & 1) == (p & 1)) {
                #pragma unroll
                for (int mf = 0; mf < 4; ++mf)
                    #pragma unroll
                    for (int i = 0; i < 4; ++i)
                        red[w][mf * 16 + (l >> 4) * 4 + i][l & 7] = acc[mf][nf][i];
            }
            __syncthreads();
            {
                float v0 = red[0][r][cb] + red[1][r][cb] + red[2][r][cb] + red[3][r][cb];
                float v1 = red[0][r][cb + 1] + red[1][r][cb + 1] + red[2][r][cb + 1] + red[3][r][cb + 1];
                int j = n0 + p * 8 + cb;
                v0 += px[p][0]; v1 += px[p][1];
                if (grp == 0) {
                    float g0 = 1.f / (1.f + __expf(-v0));
                    float g1 = 1.f / (1.f + __expf(-v1));
                    if (lowhalf) {
                        st4_sc(P.RH1 + r * 1024 + j, pack_bf16(g0 * pa[p][0], g1 * pa[p][1]));
                    } else {
                        st8_sc(P.U1 + r * 1024 + j - 1024, mk2(g0, g1));
                    }
                } else if (grp == 1) {
                    float cc0 = tanhf(v0), cc1 = tanhf(v1);
                    float hn0 = pa[p][0] * hreg[p][0] + (1.f - pa[p][0]) * cc0;
                    float hn1 = pa[p][1] * hreg[p][1] + (1.f - pa[p][1]) * cc1;
                    hreg[p] = mk2(hn0, hn1);
                    st8_sc(P.H1F + r * 1024 + j, hreg[p]);
                    unsigned pk = pack_bf16(hn0, hn1);
                    st4_sc(P.X2 + r * 2048 + j, pk);
                    st4_sc(x2c + r * 2048 + j, pk);
                } else if (grp == 2) {
                    float g0 = 1.f / (1.f + __expf(-v0));
                    float g1 = 1.f / (1.f + __expf(-v1));
                    if (lowhalf) {
                        st4_sc(x2c + r * 2048 + 1024 + j, pack_bf16(g0 * pa[p][0], g1 * pa[p][1]));
                    } else {
                        st8_sc(P.U2 + r * 1024 + j - 1024, mk2(g0, g1));
                    }
                } else {
                    float cc0 = tanhf(v0), cc1 = tanhf(v1);
                    float hn0 = pa[p][0] * hreg[p][0] + (1.f - pa[p][0]) * cc0;
                    float hn1 = pa[p][1] * hreg[p][1] + (1.f - pa[p][1]) * cc1;
                    hreg[p] = mk2(hn0, hn1);
                    st8_sc(P.H2F + r * 1024 + j, hreg[p]);
                    unsigned pk = pack_bf16(hn0, hn1);
                    st4_sc(P.X2 + r * 2048 + 1024 + j, pk);
                    *reinterpret_cast<unsigned*>(P.YS + ((size_t)r * kT + t) * 1024 + j) = pk;
                }
            }
            __syncthreads();
        }

        // release: drain all stores, barrier, publish flag.
        asm volatile("s_waitcnt vmcnt(0)" ::: "memory");
        __syncthreads();
        if (tid == 0)
            st4_sc((void*)&F[(size_t)blk * 16], ut + 1);
    }
}

// ---------------- logits GEMM (r12 single-buffer structure + LDS XOR-swizzle) ----
// GL2LDS writes LINEARLY; swizzle achieved by pre-swizzling the GLOBAL source
// granule (rule 21 / m173): LDS granule (row,g) holds global granule g^(row&7).
// Reads apply the same XOR -> 16 lanes spread over 8 bank-quads (2-way, free)
// instead of 16-way conflict on 128B-stride rows.
// PM[c][row] (f32x2): per-row (max, sumexp) over 64-col chunk c (c in [0,256)).
__global__ __launch_bounds__(256) void logits_gemm(
    const bf16_t* __restrict__ Amat,   // [kBT][kH]
    const bf16_t* __restrict__ Bt,     // [kV][kH]
    const float* __restrict__ bias,    // [kV]
    float* __restrict__ out,           // [kBT][kV]
    float* __restrict__ PM) {          // [256][kBT][2]
    __shared__ __align__(16) char As[128 * 128];   // [128 rows][64 bf16 = 128 B]
    __shared__ __align__(16) char Bs[128 * 128];
    const int tid = threadIdx.x;
    const int w = tid >> 6, l = tid & 63;
    const int wr = w >> 1, wc = w & 1;
    const int lr = l & 15, lk8 = (l >> 4) * 8;
    // bijective XCD swizzle (16384 blocks, 16384 % 8 == 0)
    int lin = blockIdx.y * gridDim.x + blockIdx.x;
    int s = (lin & 7) * 2048 + (lin >> 3);
    const int row0 = (s >> 7) * 128, col0 = (s & 127) * 128;

    int srow[4], scolsrc[4], sdst[4];
    #pragma unroll
    for (int v = 0; v < 4; ++v) {
        int idx = v * 256 + tid;                 // 16B chunk index in [0,2048)
        int row = idx >> 3, g = idx & 7;
        srow[v] = row;
        scolsrc[v] = (g ^ (row & 7)) * 8;        // pre-swizzled global col (elems)
        sdst[v] = idx * 16;                      // linear LDS byte offset
    }

    f32x4 acc[4][4] = {};
    for (int kt = 0; kt < 16; ++kt) {
        int ko = kt * 64;
        #pragma unroll
        for (int v = 0; v < 4; ++v) {
            GL2LDS(Amat + (size_t)(row0 + srow[v]) * kH + ko + scolsrc[v], As + sdst[v]);
            GL2LDS(Bt + (size_t)(col0 + srow[v]) * kH + ko + scolsrc[v], Bs + sdst[v]);
        }
        asm volatile("s_waitcnt vmcnt(0)" ::: "memory");
        __syncthreads();
        #pragma unroll
        for (int ks = 0; ks < 2; ++ks) {
            int kb2 = (ks * 32 + lk8) * 2;       // byte col within 128B row
            bf16x8 af[4], bfv[4];
            #pragma unroll
            for (int mf = 0; mf < 4; ++mf) {
                int rr = wr * 64 + mf * 16 + lr;
                af[mf] = *reinterpret_cast<const bf16x8*>(As + rr * 128 + (kb2 ^ ((rr & 7) << 4)));
            }
            #pragma unroll
            for (int nf = 0; nf < 4; ++nf) {
                int rr = wc * 64 + nf * 16 + lr;
                bfv[nf] = *reinterpret_cast<const bf16x8*>(Bs + rr * 128 + (kb2 ^ ((rr & 7) << 4)));
            }
            #pragma unroll
            for (int mf = 0; mf < 4; ++mf)
                #pragma unroll
                for (int nf = 0; nf < 4; ++nf)
                    acc[mf][nf] = __builtin_amdgcn_mfma_f32_16x16x32_bf16(af[mf], bfv[nf], acc[mf][nf], 0, 0, 0);
        }
        __syncthreads();
    }
    // epilogue: bias add + store + per-row (max,sumexp) partial over this wave's 64 cols
    const int chunk = (col0 >> 6) + wc;          // [0,256)
    #pragma unroll
    for (int mf = 0; mf < 4; ++mf) {
        #pragma unroll
        for (int i = 0; i < 4; ++i) {
            int row = row0 + wr * 64 + mf * 16 + (l >> 4) * 4 + i;
            float vals[4];
            #pragma unroll
            for (int nf = 0; nf < 4; ++nf) {
                int col = col0 + wc * 64 + nf * 16 + lr;
                vals[nf] = acc[mf][nf][i] + bias[col];
                out[(size_t)row * kV + col] = vals[nf];
            }
            float m = fmaxf(fmaxf(vals[0], vals[1]), fmaxf(vals[2], vals[3]));
            float sm = __expf(vals[0] - m) + __expf(vals[1] - m)
                     + __expf(vals[2] - m) + __expf(vals[3] - m);
            #pragma unroll
            for (int d = 1; d < 16; d <<= 1) {
                float m2 = __shfl_xor(m, d);
                float s2 = __shfl_xor(sm, d);
                float M = fmaxf(m, m2);
                sm = sm * __expf(m - M) + s2 * __expf(m2 - M);
                m = M;
            }
            if (lr == 0)
                *reinterpret_cast<f32x2*>(PM + ((size_t)chunk * kBT + row) * 2) = mk2(m, sm);
        }
    }
}

// ---------------- NLL finalize: combine 256 chunk-partials per row ----------------
__global__ __launch_bounds__(256) void nll_finalize(const float* __restrict__ PM,
                                                    const float* __restrict__ logits,
                                                    const int* __restrict__ targets,
                                                    float* __restrict__ nll) {
    int row = blockIdx.x * 256 + threadIdx.x;
    float m = -1e30f, s = 0.f;
    #pragma unroll 4
    for (int c = 0; c < 256; ++c) {
        f32x2 p = *reinterpret_cast<const f32x2*>(PM + ((size_t)c * kBT + row) * 2);
        float M = fmaxf(m, p[0]);
        s = s * __expf(m - M) + p[1] * __expf(p[0] - M);
        m = M;
    }
    float tl = logits[(size_t)row * kV + targets[row]];
    nll[row] = m + __logf(s) - tl;
}

__global__ __launch_bounds__(256) void loss_reduce(const float* __restrict__ nll,
                                                   float* __restrict__ out) {
    __shared__ float sm[256];
    int tid = threadIdx.x;
    float s = 0.f;
    for (int i = tid; i < kBT; i += 256) s += nll[i];
    sm[tid] = s;
    __syncthreads();
    for (int off = 128; off; off >>= 1) {
        if (tid < off) sm[tid] += sm[tid + off];
        __syncthreads();
    }
    if (tid == 0) out[0] = sm[0] / (float)kBT;
}

// ---------------- host ----------------
extern "C" void kernel_launch(void* const* d_in, const int* in_sizes, int n_in,
                              void* d_out, int out_size, void* d_ws, size_t ws_size,
                              hipStream_t stream) {
    const int*   ids = (const int*)d_in[0];
    const int*   tgt = (const int*)d_in[1];
    const float* emb = (const float*)d_in[2];
    const float* Wg1 = (const float*)d_in[3];
    const float* bg1 = (const float*)d_in[4];
    const float* Wc1 = (const float*)d_in[5];
    const float* bc1 = (const float*)d_in[6];
    const float* Wg2 = (const float*)d_in[7];
    const float* bg2 = (const float*)d_in[8];
    const float* Wc2 = (const float*)d_in[9];
    const float* bc2 = (const float*)d_in[10];
    const float* sw  = (const float*)d_in[11];
    const float* sb  = (const float*)d_in[12];
    float* out = (float*)d_out;

    char* ws = (char*)d_ws;
    size_t off = 0;
    auto alloc = [&](size_t bytes) -> void* {
        void* p = ws + off;
        off += (bytes + 255) & ~(size_t)255;
        return p;
    };
    bf16_t* WG1HT = (bf16_t*)alloc((size_t)2048 * 1024 * 2);
    bf16_t* WC1HT = (bf16_t*)alloc((size_t)1024 * 1024 * 2);
    bf16_t* WG2T  = (bf16_t*)alloc((size_t)2048 * 2048 * 2);
    bf16_t* WC2T  = (bf16_t*)alloc((size_t)1024 * 2048 * 2);
    bf16_t* SWT   = (bf16_t*)alloc((size_t)kV * kH * 2);
    bf16_t* WG1XT = (bf16_t*)alloc((size_t)2048 * kE * 2);
    bf16_t* WC1XT = (bf16_t*)alloc((size_t)1024 * kE * 2);
    bf16_t* XB    = (bf16_t*)alloc((size_t)kBT * kE * 2);
    float*  XG1   = (float*)alloc((size_t)kBT * 2048 * 4);
    float*  XC1   = (float*)alloc((size_t)kBT * 1024 * 4);
    bf16_t* YS    = (bf16_t*)alloc((size_t)kBT * kH * 2);
    float*  NLL   = (float*)alloc((size_t)kBT * 4);
    float*  PM    = (float*)alloc((size_t)256 * kBT * 2 * 4);
    // ---- contiguous zero region start ----
    char*   zbase = ws + off;
    float*  H1F   = (float*)alloc((size_t)kB * kH * 4);
    float*  H2F   = (float*)alloc((size_t)kB * kH * 4);
    float*  U1    = (float*)alloc((size_t)kB * kH * 4);
    float*  U2    = (float*)alloc((size_t)kB * kH * 4);
    bf16_t* X2    = (bf16_t*)alloc((size_t)kB * 2048 * 2);
    bf16_t* X2C0  = (bf16_t*)alloc((size_t)kB * 2048 * 2);
    bf16_t* X2C1  = (bf16_t*)alloc((size_t)kB * 2048 * 2);
    bf16_t* RH1   = (bf16_t*)alloc((size_t)kB * kH * 2);
    unsigned* FLAGS = (unsigned*)alloc(192 * 16 * 4);
    size_t zlen = (ws + off) - zbase;
    // ---- contiguous zero region end ----

    // weight conversions (bf16, [N][K] layout)
    transpose_to_bf16<<<dim3(64, 32), dim3(32, 8), 0, stream>>>(Wg1 + (size_t)kE * 2048, WG1HT, 1024, 2048);
    transpose_to_bf16<<<dim3(32, 32), dim3(32, 8), 0, stream>>>(Wc1 + (size_t)kE * 1024, WC1HT, 1024, 1024);
    transpose_to_bf16<<<dim3(64, 64), dim3(32, 8), 0, stream>>>(Wg2, WG2T, 2048, 2048);
    transpose_to_bf16<<<dim3(32, 64), dim3(32, 8), 0, stream>>>(Wc2, WC2T, 2048, 1024);
    transpose_to_bf16<<<dim3(512, 32), dim3(32, 8), 0, stream>>>(sw, SWT, 1024, 16384);
    transpose_to_bf16<<<dim3(64, 4), dim3(32, 8), 0, stream>>>(Wg1, WG1XT, 128, 2048);
    transpose_to_bf16<<<dim3(32, 4), dim3(32, 8), 0, stream>>>(Wc1, WC1XT, 128, 1024);

    embed_gather<<<kBT / 16, 256, 0, stream>>>(ids, emb, XB);
    xpre_gemm<<<dim3(16, kBT / 128), 256, 0, stream>>>(XB, WG1XT, bg1, XG1, 2048);
    xpre_gemm<<<dim3(8, kBT / 128), 256, 0, stream>>>(XB, WC1XT, bc1, XC1, 1024);
    zero_bytes<<<256, 256, 0, stream>>>(zbase, zlen);

    PP prm;
    prm.WG1HT = WG1HT; prm.WC1HT = WC1HT; prm.WG2T = WG2T; prm.WC2T = WC2T;
    prm.XG1 = XG1; prm.XC1 = XC1; prm.bg2 = bg2; prm.bc2 = bc2;
    prm.H1F = H1F; prm.H2F = H2F; prm.U1 = U1; prm.U2 = U2;
    prm.X2 = X2; prm.X2C0 = X2C0; prm.X2C1 = X2C1; prm.RH1 = RH1; prm.YS = YS;
    prm.flags = FLAGS;
    void* args[] = { &prm };
    hipLaunchCooperativeKernel((const void*)rnn_persistent, dim3(192), dim3(256), args, 0, stream);

    logits_gemm<<<dim3(kV / 128, kBT / 128), 256, 0, stream>>>(YS, SWT, sb, out, PM);
    nll_finalize<<<kBT / 256, 256, 0, stream>>>(PM, out, tgt, NLL);
    loss_reduce<<<1, 256, 0, stream>>>(NLL, out + (size_t)kBT * kV);
}